// Round 5
// baseline (351.378 us; speedup 1.0000x reference)
//
#include <hip/hip_runtime.h>
#include <hip/hip_bf16.h>

#define HIDDEN 1024
#define INTER 2048
#define NE 8
#define GS 128
#define TOKENS 4096
#define MAXROWS 9216  // 8192 routed rows + 8*128 padding capacity
#define MAXTILES 72

typedef __bf16 bf16x8 __attribute__((ext_vector_type(8)));
typedef float f32x4 __attribute__((ext_vector_type(4)));

// ---- ws layout (bytes) ----
#define OFF_TOPKI 0u               // int[4096][2]
#define OFF_TOPKW 32768u           // float[4096][2]
#define OFF_CTRL  65536u           // int[32]: [0..7]=counts [16..23]=offsets [24]=padded total [25]=ntiles
#define OFF_TOK   66048u           // int[MAXROWS]
#define OFF_SLOT  102912u          // int[TOKENS*2]
#define OFF_TILE  135680u          // int[MAXTILES] tile -> (e<<20 | row0)
#define OFF_XG    139776u          // bf16[MAXROWS][HIDDEN]   (aliased as y after gemm1)
#define OFF_A     19014144u        // bf16[MAXROWS][INTER]
#define OFF_W1D   56762880u        // bf16[NE][4096][HIDDEN]
#define OFF_W2D   123871744u       // bf16[NE][1024][INTER]   -> 157426176 total

__device__ __forceinline__ unsigned short f2bf(float f) {
  union { float f; unsigned int u; } v; v.f = f;
  unsigned int r = (v.u + 0x7FFFu + ((v.u >> 16) & 1u)) >> 16;
  return (unsigned short)r;
}
__device__ __forceinline__ float bf2f(unsigned int u) {
  union { unsigned int u; float f; } v; v.u = u << 16;
  return v.f;
}
__device__ __forceinline__ unsigned int pack2(unsigned short lo, unsigned short hi) {
  return (unsigned int)lo | ((unsigned int)hi << 16);
}

// async global->LDS, 16B per lane. LDS dest is wave-uniform base + lane*16.
typedef const __attribute__((address_space(1))) unsigned int GAS;
typedef __attribute__((address_space(3))) unsigned int LAS;
__device__ __forceinline__ void gload16(const unsigned short* g, unsigned short* l) {
  __builtin_amdgcn_global_load_lds((GAS*)g, (LAS*)l, 16, 0, 0);
}

// XOR swizzle (BK=64, 8 x 16B-blocks per row): LDS slot (row, cblk) holds
// global (row, cblk ^ (row&7)). Any 8 consecutive lanes of a ds_read_b128
// fragment read cover all 8 bank-groups exactly once -> conflict-free.

// ------------- prep: router (blocks 0..1023) + deq1 (blocks 1024..17407) ----
__global__ __launch_bounds__(256) void k_prep(const float* __restrict__ x,
    const float* __restrict__ rw, int* __restrict__ topki, float* __restrict__ topkw,
    const int* __restrict__ w1, const float* __restrict__ w1s,
    unsigned short* __restrict__ w1d) {
  int bid = blockIdx.x, tid = threadIdx.x;
  if (bid >= 1024) {
    // ---- deq1: int4 -> bf16, 512 int32 per row, 8 scales per row ----
    int gid = (bid - 1024) * 256 + tid;
    int i4 = gid * 4;
    int r = i4 >> 9;
    int i = i4 & 511;
    float s = w1s[r * 8 + (i >> 6)];
    int4 p = *reinterpret_cast<const int4*>(w1 + (size_t)i4);
    int pv[4] = { p.x, p.y, p.z, p.w };
    uint4 o; unsigned int ov[4];
#pragma unroll
    for (int j = 0; j < 4; j++) {
      float lo = (float)((pv[j] & 15) - 8) * s;
      float hi = (float)(((pv[j] >> 4) & 15) - 8) * s;
      ov[j] = pack2(f2bf(lo), f2bf(hi));
    }
    o.x = ov[0]; o.y = ov[1]; o.z = ov[2]; o.w = ov[3];
    *reinterpret_cast<uint4*>(w1d + ((size_t)r << 10) + 2 * i) = o;
    return;
  }
  // ---- router ----
  int wave = tid >> 6, lane = tid & 63;
  int t = bid * 4 + wave;
  float acc[NE];
#pragma unroll
  for (int e = 0; e < NE; e++) acc[e] = 0.f;
  const float* xr = x + (size_t)t * HIDDEN;
  for (int i = lane; i < HIDDEN; i += 64) {
    float xv = xr[i];
#pragma unroll
    for (int e = 0; e < NE; e++) acc[e] += xv * rw[e * HIDDEN + i];
  }
#pragma unroll
  for (int e = 0; e < NE; e++) {
    float v = acc[e];
    for (int off = 32; off > 0; off >>= 1) v += __shfl_down(v, off, 64);
    acc[e] = v;
  }
  if (lane == 0) {
    int b0 = 0; float s0 = acc[0];
#pragma unroll
    for (int e = 1; e < NE; e++) if (acc[e] > s0) { s0 = acc[e]; b0 = e; }
    int b1 = -1; float s1 = -3.0e38f;
#pragma unroll
    for (int e = 0; e < NE; e++) if (e != b0 && acc[e] > s1) { s1 = acc[e]; b1 = e; }
    float w0 = 1.f / (1.f + __expf(s1 - s0));
    topki[t * 2] = b0; topki[t * 2 + 1] = b1;
    topkw[t * 2] = w0; topkw[t * 2 + 1] = 1.f - w0;
  }
}

// ------- route2 (1 block): hist + offsets + tilemap + pad fill + scatter ----
__global__ __launch_bounds__(256) void k_route2(const int* __restrict__ topki,
    int* __restrict__ ctrl, int* __restrict__ tok, int* __restrict__ slots,
    int* __restrict__ tilemap) {
  __shared__ int h[NE], off[NE], cnt[NE];
  int tid = threadIdx.x;
  if (tid < NE) h[tid] = 0;
  __syncthreads();
  for (int i = tid; i < TOKENS * 2; i += 256) atomicAdd(&h[topki[i]], 1);
  __syncthreads();
  if (tid == 0) {
    int run = 0, t = 0;
    for (int e = 0; e < NE; e++) {
      int c = h[e];
      ctrl[e] = c; ctrl[16 + e] = run; off[e] = run;
      int pc = (c + 127) & ~127;
      for (int mt = 0; mt < (pc >> 7); mt++) tilemap[t++] = (e << 20) | (run + mt * 128);
      run += pc;
    }
    ctrl[24] = run; ctrl[25] = t;
  }
  __syncthreads();
#pragma unroll
  for (int e = 0; e < NE; e++) {
    int c = h[e], pc = (c + 127) & ~127;
    for (int i = c + tid; i < pc; i += 256) tok[off[e] + i] = -1;
  }
  if (tid < NE) cnt[tid] = off[tid];
  __syncthreads();
  for (int i = tid; i < TOKENS * 2; i += 256) {
    int e = topki[i];
    int p = atomicAdd(&cnt[e], 1);
    tok[p] = i >> 1;
    slots[i] = p;
  }
}

// --------------- gather x rows (fp32 -> bf16), zero pad rows ---------------
__global__ __launch_bounds__(256) void k_gather(const float* __restrict__ x,
    const int* __restrict__ ctrl, const int* __restrict__ tok,
    unsigned short* __restrict__ xg) {
  int s = blockIdx.x;
  if (s >= ctrl[24]) return;
  int t = tok[s];
  int c = threadIdx.x * 4;
  unsigned short* dst = xg + (size_t)s * HIDDEN + c;
  if (t < 0) {
    uint2 z; z.x = 0u; z.y = 0u;
    *reinterpret_cast<uint2*>(dst) = z;
  } else {
    float4 v = *reinterpret_cast<const float4*>(x + (size_t)t * HIDDEN + c);
    uint2 o;
    o.x = pack2(f2bf(v.x), f2bf(v.y));
    o.y = pack2(f2bf(v.z), f2bf(v.w));
    *reinterpret_cast<uint2*>(dst) = o;
  }
}

// --- GEMM1 (blocks 0..2303) + deq2 (blocks 2304..10495) --------------------
// GEMM1: 128 rows x (64 gate + 64 up), BK=64, swizzled LDS, async staging.
__global__ __launch_bounds__(256) void k_gemm1x(
    const unsigned short* __restrict__ xg, const unsigned short* __restrict__ w1d,
    const int* __restrict__ ctrl, const int* __restrict__ tilemap,
    unsigned short* __restrict__ a_out,
    const int* __restrict__ w2, const float* __restrict__ w2s,
    unsigned short* __restrict__ w2d) {
  __shared__ unsigned short sA[128 * 64];   // 16 KB
  __shared__ unsigned short sBg[64 * 64];   // 8 KB
  __shared__ unsigned short sBu[64 * 64];   // 8 KB
  int bid = blockIdx.x, tid = threadIdx.x;
  if (bid >= 2304) {
    // ---- deq2: 1024 int32 per row, 16 scales per row ----
    int gid = (bid - 2304) * 256 + tid;
    int i4 = gid * 4;
    int r = i4 >> 10;
    int i = i4 & 1023;
    float s = w2s[r * 16 + (i >> 6)];
    int4 p = *reinterpret_cast<const int4*>(w2 + (size_t)i4);
    int pv[4] = { p.x, p.y, p.z, p.w };
    uint4 o; unsigned int ov[4];
#pragma unroll
    for (int j = 0; j < 4; j++) {
      float lo = (float)((pv[j] & 15) - 8) * s;
      float hi = (float)(((pv[j] >> 4) & 15) - 8) * s;
      ov[j] = pack2(f2bf(lo), f2bf(hi));
    }
    o.x = ov[0]; o.y = ov[1]; o.z = ov[2]; o.w = ov[3];
    *reinterpret_cast<uint4*>(w2d + ((size_t)r << 11) + 2 * i) = o;
    return;
  }
  int nt = bid & 31, tile = bid >> 5;
  if (tile >= ctrl[25]) return;
  int tm = tilemap[tile];
  int e = tm >> 20, row0 = tm & 0xFFFFF;
  int n0 = nt * 64;
  int wave = tid >> 6, lane = tid & 63;
  int ln = lane & 15, quad = lane >> 4;
  int wr = (wave & 1) * 64, wc = (wave >> 1) * 32;

  // staging: slot = tid + 256*j ; row = slot>>3, cblk = slot&7, swizzled col
  const unsigned short* gA[4];
  const unsigned short* gBg[2];
  const unsigned short* gBu[2];
#pragma unroll
  for (int j = 0; j < 4; j++) {
    int slot = tid + 256 * j, row = slot >> 3;
    int col = ((slot & 7) ^ (row & 7)) * 8;
    gA[j] = xg + (size_t)(row0 + row) * HIDDEN + col;
  }
#pragma unroll
  for (int j = 0; j < 2; j++) {
    int slot = tid + 256 * j, row = slot >> 3;
    int col = ((slot & 7) ^ (row & 7)) * 8;
    gBg[j] = w1d + ((size_t)e * 4096 + n0 + row) * HIDDEN + col;
    gBu[j] = gBg[j] + (size_t)INTER * HIDDEN;
  }

  f32x4 aG[4][2] = {}, aU[4][2] = {};
  for (int k0 = 0; k0 < HIDDEN; k0 += 64) {
    __syncthreads();
#pragma unroll
    for (int j = 0; j < 4; j++) gload16(gA[j] + k0, sA + (tid + 256 * j) * 8);
#pragma unroll
    for (int j = 0; j < 2; j++) {
      gload16(gBg[j] + k0, sBg + (tid + 256 * j) * 8);
      gload16(gBu[j] + k0, sBu + (tid + 256 * j) * 8);
    }
    __syncthreads();
#pragma unroll
    for (int kh = 0; kh < 2; kh++) {
      bf16x8 af[4], bg[2], bu[2];
#pragma unroll
      for (int m = 0; m < 4; m++) {
        int ar = wr + m * 16 + ln;
        af[m] = *reinterpret_cast<const bf16x8*>(
            &sA[ar * 64 + ((((kh << 2) | quad)) ^ (ar & 7)) * 8]);
      }
#pragma unroll
      for (int n = 0; n < 2; n++) {
        int br = wc + n * 16 + ln;
        int c = ((((kh << 2) | quad)) ^ (br & 7)) * 8;
        bg[n] = *reinterpret_cast<const bf16x8*>(&sBg[br * 64 + c]);
        bu[n] = *reinterpret_cast<const bf16x8*>(&sBu[br * 64 + c]);
      }
#pragma unroll
      for (int m = 0; m < 4; m++)
#pragma unroll
        for (int n = 0; n < 2; n++) {
          aG[m][n] = __builtin_amdgcn_mfma_f32_16x16x32_bf16(af[m], bg[n], aG[m][n], 0, 0, 0);
          aU[m][n] = __builtin_amdgcn_mfma_f32_16x16x32_bf16(af[m], bu[n], aU[m][n], 0, 0, 0);
        }
    }
  }
#pragma unroll
  for (int m = 0; m < 4; m++)
#pragma unroll
    for (int n = 0; n < 2; n++) {
      int col = n0 + wc + n * 16 + ln;
#pragma unroll
      for (int r = 0; r < 4; r++) {
        float g = aG[m][n][r], u = aU[m][n][r];
        float act = (g / (1.f + __expf(-g))) * u;
        int row = row0 + wr + m * 16 + quad * 4 + r;
        a_out[(size_t)row * INTER + col] = f2bf(act);
      }
    }
}

// --------------- GEMM2: y[slot] = a @ w2^T, 128x128, BK=64 -----------------
__global__ __launch_bounds__(256) void k_gemm2(
    const unsigned short* __restrict__ a_in, const unsigned short* __restrict__ w2d,
    const int* __restrict__ ctrl, const int* __restrict__ tilemap,
    unsigned short* __restrict__ y) {
  __shared__ unsigned short sA[128 * 64];   // 16 KB
  __shared__ unsigned short sB[128 * 64];   // 16 KB
  int bid = blockIdx.x, tid = threadIdx.x;
  int nt = bid & 7, tile = bid >> 3;
  if (tile >= ctrl[25]) return;
  int tm = tilemap[tile];
  int e = tm >> 20, row0 = tm & 0xFFFFF;
  int n0 = nt * 128;
  int wave = tid >> 6, lane = tid & 63;
  int ln = lane & 15, quad = lane >> 4;
  int wr = (wave & 1) * 64, wc = (wave >> 1) * 64;

  const unsigned short* gA[4];
  const unsigned short* gB[4];
#pragma unroll
  for (int j = 0; j < 4; j++) {
    int slot = tid + 256 * j, row = slot >> 3;
    int col = ((slot & 7) ^ (row & 7)) * 8;
    gA[j] = a_in + (size_t)(row0 + row) * INTER + col;
    gB[j] = w2d + ((size_t)e * 1024 + n0 + row) * INTER + col;
  }

  f32x4 acc[4][4] = {};
  for (int k0 = 0; k0 < INTER; k0 += 64) {
    __syncthreads();
#pragma unroll
    for (int j = 0; j < 4; j++) {
      gload16(gA[j] + k0, sA + (tid + 256 * j) * 8);
      gload16(gB[j] + k0, sB + (tid + 256 * j) * 8);
    }
    __syncthreads();
#pragma unroll
    for (int kh = 0; kh < 2; kh++) {
      bf16x8 af[4], bf_[4];
#pragma unroll
      for (int m = 0; m < 4; m++) {
        int ar = wr + m * 16 + ln;
        af[m] = *reinterpret_cast<const bf16x8*>(
            &sA[ar * 64 + ((((kh << 2) | quad)) ^ (ar & 7)) * 8]);
      }
#pragma unroll
      for (int n = 0; n < 4; n++) {
        int br = wc + n * 16 + ln;
        bf_[n] = *reinterpret_cast<const bf16x8*>(
            &sB[br * 64 + ((((kh << 2) | quad)) ^ (br & 7)) * 8]);
      }
#pragma unroll
      for (int m = 0; m < 4; m++)
#pragma unroll
        for (int n = 0; n < 4; n++)
          acc[m][n] = __builtin_amdgcn_mfma_f32_16x16x32_bf16(af[m], bf_[n], acc[m][n], 0, 0, 0);
    }
  }
#pragma unroll
  for (int m = 0; m < 4; m++)
#pragma unroll
    for (int n = 0; n < 4; n++) {
      int col = n0 + wc + n * 16 + ln;
#pragma unroll
      for (int r = 0; r < 4; r++) {
        int row = row0 + wr + m * 16 + quad * 4 + r;
        y[(size_t)row * HIDDEN + col] = f2bf(acc[m][n][r]);
      }
    }
}

// --------------- combine: out[t] = g0*y[s0] + g1*y[s1] ---------------------
__global__ __launch_bounds__(256) void k_combine(const unsigned short* __restrict__ y,
    const int* __restrict__ slots, const float* __restrict__ topkw,
    float* __restrict__ out) {
  int t = blockIdx.x;
  int c = threadIdx.x * 4;
  int s0 = slots[t * 2], s1 = slots[t * 2 + 1];
  float g0 = topkw[t * 2], g1 = topkw[t * 2 + 1];
  uint2 va = *reinterpret_cast<const uint2*>(y + (size_t)s0 * HIDDEN + c);
  uint2 vb = *reinterpret_cast<const uint2*>(y + (size_t)s1 * HIDDEN + c);
  float4 o;
  o.x = g0 * bf2f(va.x & 0xffffu) + g1 * bf2f(vb.x & 0xffffu);
  o.y = g0 * bf2f(va.x >> 16)     + g1 * bf2f(vb.x >> 16);
  o.z = g0 * bf2f(va.y & 0xffffu) + g1 * bf2f(vb.y & 0xffffu);
  o.w = g0 * bf2f(va.y >> 16)     + g1 * bf2f(vb.y >> 16);
  *reinterpret_cast<float4*>(out + (size_t)t * HIDDEN + c) = o;
}

extern "C" void kernel_launch(void* const* d_in, const int* in_sizes, int n_in,
                              void* d_out, int out_size, void* d_ws, size_t ws_size,
                              hipStream_t stream) {
  const float* x   = (const float*)d_in[0];
  const float* rw  = (const float*)d_in[1];
  const int*   w1  = (const int*)d_in[2];
  const float* w1s = (const float*)d_in[3];
  const int*   w2  = (const int*)d_in[4];
  const float* w2s = (const float*)d_in[5];
  float* out = (float*)d_out;
  char* ws = (char*)d_ws;

  int*   topki = (int*)(ws + OFF_TOPKI);
  float* topkw = (float*)(ws + OFF_TOPKW);
  int*   ctrl  = (int*)(ws + OFF_CTRL);
  int*   tok   = (int*)(ws + OFF_TOK);
  int*   slots = (int*)(ws + OFF_SLOT);
  int*   tilemap = (int*)(ws + OFF_TILE);
  unsigned short* xg  = (unsigned short*)(ws + OFF_XG);  // aliased as y after gemm1
  unsigned short* a   = (unsigned short*)(ws + OFF_A);
  unsigned short* w1d = (unsigned short*)(ws + OFF_W1D);
  unsigned short* w2d = (unsigned short*)(ws + OFF_W2D);

  k_prep<<<1024 + 16384, 256, 0, stream>>>(x, rw, topki, topkw, w1, w1s, w1d);
  k_route2<<<1, 256, 0, stream>>>(topki, ctrl, tok, slots, tilemap);
  k_gather<<<MAXROWS, 256, 0, stream>>>(x, ctrl, tok, xg);
  k_gemm1x<<<2304 + 8192, 256, 0, stream>>>(xg, w1d, ctrl, tilemap, a, w2, w2s, w2d);
  k_gemm2<<<8 * MAXTILES, 256, 0, stream>>>(a, w2d, ctrl, tilemap, xg /* y aliases xg */);
  k_combine<<<TOKENS, 256, 0, stream>>>(xg, slots, topkw, out);
}

// Round 6
// 333.050 us; speedup vs baseline: 1.0550x; 1.0550x over previous
//
#include <hip/hip_runtime.h>
#include <hip/hip_bf16.h>

#define HIDDEN 1024
#define INTER 2048
#define NE 8
#define GS 128
#define TOKENS 4096
#define MAXROWS 9216  // 8192 routed rows + 8*128 padding capacity
#define MAXTILES 72

typedef __bf16 bf16x8 __attribute__((ext_vector_type(8)));
typedef float f32x4 __attribute__((ext_vector_type(4)));

// ---- ws layout (bytes) ----
#define OFF_TOPKI 0u               // int[4096][2]
#define OFF_TOPKW 32768u           // float[4096][2]
#define OFF_CTRL  65536u           // int[32]: [0..7]=counts [16..23]=offsets [24]=padded total [25]=ntiles
#define OFF_TOK   66048u           // int[MAXROWS]
#define OFF_SLOT  102912u          // int[TOKENS*2]
#define OFF_TILE  135680u          // int[MAXTILES] tile -> (e<<20 | row0)
#define OFF_XG    139776u          // bf16[MAXROWS][HIDDEN]   (aliased as y after gemm1)
#define OFF_A     19014144u        // bf16[MAXROWS][INTER]
#define OFF_W1D   56762880u        // bf16[NE][4096][HIDDEN]
#define OFF_W2D   123871744u       // bf16[NE][1024][INTER]   -> 157426176 total

__device__ __forceinline__ unsigned short f2bf(float f) {
  union { float f; unsigned int u; } v; v.f = f;
  unsigned int r = (v.u + 0x7FFFu + ((v.u >> 16) & 1u)) >> 16;
  return (unsigned short)r;
}
__device__ __forceinline__ float bf2f(unsigned int u) {
  union { unsigned int u; float f; } v; v.u = u << 16;
  return v.f;
}
__device__ __forceinline__ unsigned int pack2(unsigned short lo, unsigned short hi) {
  return (unsigned int)lo | ((unsigned int)hi << 16);
}

// async global->LDS, 16B per lane. LDS dest is wave-uniform base + lane*16.
typedef const __attribute__((address_space(1))) unsigned int GAS;
typedef __attribute__((address_space(3))) unsigned int LAS;
__device__ __forceinline__ void gload16(const unsigned short* g, unsigned short* l) {
  __builtin_amdgcn_global_load_lds((GAS*)g, (LAS*)l, 16, 0, 0);
}

// XOR swizzle (BK=32, 4 x 16B-blocks per row): LDS slot (row, cblk) holds
// global (row, cblk ^ ((row>>1)&3)). Measured 0 bank conflicts (R4).

// ---- prep: router (0..1023) + deq1 (1024..17407) + deq2 (17408..25599) ----
// No LDS anywhere -> all block types run at full occupancy.
__global__ __launch_bounds__(256) void k_prep(const float* __restrict__ x,
    const float* __restrict__ rw, int* __restrict__ topki, float* __restrict__ topkw,
    const int* __restrict__ w1, const float* __restrict__ w1s,
    unsigned short* __restrict__ w1d,
    const int* __restrict__ w2, const float* __restrict__ w2s,
    unsigned short* __restrict__ w2d) {
  int bid = blockIdx.x, tid = threadIdx.x;
  if (bid >= 17408) {
    // ---- deq2: 1024 int32 per row, 16 scales per row ----
    int gid = (bid - 17408) * 256 + tid;
    int i4 = gid * 4;
    int r = i4 >> 10;
    int i = i4 & 1023;
    float s = w2s[r * 16 + (i >> 6)];
    int4 p = *reinterpret_cast<const int4*>(w2 + (size_t)i4);
    int pv[4] = { p.x, p.y, p.z, p.w };
    uint4 o; unsigned int ov[4];
#pragma unroll
    for (int j = 0; j < 4; j++) {
      float lo = (float)((pv[j] & 15) - 8) * s;
      float hi = (float)(((pv[j] >> 4) & 15) - 8) * s;
      ov[j] = pack2(f2bf(lo), f2bf(hi));
    }
    o.x = ov[0]; o.y = ov[1]; o.z = ov[2]; o.w = ov[3];
    *reinterpret_cast<uint4*>(w2d + ((size_t)r << 11) + 2 * i) = o;
    return;
  }
  if (bid >= 1024) {
    // ---- deq1: 512 int32 per row, 8 scales per row ----
    int gid = (bid - 1024) * 256 + tid;
    int i4 = gid * 4;
    int r = i4 >> 9;
    int i = i4 & 511;
    float s = w1s[r * 8 + (i >> 6)];
    int4 p = *reinterpret_cast<const int4*>(w1 + (size_t)i4);
    int pv[4] = { p.x, p.y, p.z, p.w };
    uint4 o; unsigned int ov[4];
#pragma unroll
    for (int j = 0; j < 4; j++) {
      float lo = (float)((pv[j] & 15) - 8) * s;
      float hi = (float)(((pv[j] >> 4) & 15) - 8) * s;
      ov[j] = pack2(f2bf(lo), f2bf(hi));
    }
    o.x = ov[0]; o.y = ov[1]; o.z = ov[2]; o.w = ov[3];
    *reinterpret_cast<uint4*>(w1d + ((size_t)r << 10) + 2 * i) = o;
    return;
  }
  // ---- router ----
  int wave = tid >> 6, lane = tid & 63;
  int t = bid * 4 + wave;
  float acc[NE];
#pragma unroll
  for (int e = 0; e < NE; e++) acc[e] = 0.f;
  const float* xr = x + (size_t)t * HIDDEN;
  for (int i = lane; i < HIDDEN; i += 64) {
    float xv = xr[i];
#pragma unroll
    for (int e = 0; e < NE; e++) acc[e] += xv * rw[e * HIDDEN + i];
  }
#pragma unroll
  for (int e = 0; e < NE; e++) {
    float v = acc[e];
    for (int off = 32; off > 0; off >>= 1) v += __shfl_down(v, off, 64);
    acc[e] = v;
  }
  if (lane == 0) {
    int b0 = 0; float s0 = acc[0];
#pragma unroll
    for (int e = 1; e < NE; e++) if (acc[e] > s0) { s0 = acc[e]; b0 = e; }
    int b1 = -1; float s1 = -3.0e38f;
#pragma unroll
    for (int e = 0; e < NE; e++) if (e != b0 && acc[e] > s1) { s1 = acc[e]; b1 = e; }
    float w0 = 1.f / (1.f + __expf(s1 - s0));
    topki[t * 2] = b0; topki[t * 2 + 1] = b1;
    topkw[t * 2] = w0; topkw[t * 2 + 1] = 1.f - w0;
  }
}

// ------- route2 (1 block): hist + offsets + tilemap + pad fill + scatter ----
__global__ __launch_bounds__(256) void k_route2(const int* __restrict__ topki,
    int* __restrict__ ctrl, int* __restrict__ tok, int* __restrict__ slots,
    int* __restrict__ tilemap) {
  __shared__ int h[NE], off[NE], cnt[NE];
  int tid = threadIdx.x;
  if (tid < NE) h[tid] = 0;
  __syncthreads();
  for (int i = tid; i < TOKENS * 2; i += 256) atomicAdd(&h[topki[i]], 1);
  __syncthreads();
  if (tid == 0) {
    int run = 0, t = 0;
    for (int e = 0; e < NE; e++) {
      int c = h[e];
      ctrl[e] = c; ctrl[16 + e] = run; off[e] = run;
      int pc = (c + 127) & ~127;
      for (int mt = 0; mt < (pc >> 7); mt++) tilemap[t++] = (e << 20) | (run + mt * 128);
      run += pc;
    }
    ctrl[24] = run; ctrl[25] = t;
  }
  __syncthreads();
#pragma unroll
  for (int e = 0; e < NE; e++) {
    int c = h[e], pc = (c + 127) & ~127;
    for (int i = c + tid; i < pc; i += 256) tok[off[e] + i] = -1;
  }
  if (tid < NE) cnt[tid] = off[tid];
  __syncthreads();
  for (int i = tid; i < TOKENS * 2; i += 256) {
    int e = topki[i];
    int p = atomicAdd(&cnt[e], 1);
    tok[p] = i >> 1;
    slots[i] = p;
  }
}

// --------------- gather x rows (fp32 -> bf16), zero pad rows ---------------
__global__ __launch_bounds__(256) void k_gather(const float* __restrict__ x,
    const int* __restrict__ ctrl, const int* __restrict__ tok,
    unsigned short* __restrict__ xg) {
  int s = blockIdx.x;
  if (s >= ctrl[24]) return;
  int t = tok[s];
  int c = threadIdx.x * 4;
  unsigned short* dst = xg + (size_t)s * HIDDEN + c;
  if (t < 0) {
    uint2 z; z.x = 0u; z.y = 0u;
    *reinterpret_cast<uint2*>(dst) = z;
  } else {
    float4 v = *reinterpret_cast<const float4*>(x + (size_t)t * HIDDEN + c);
    uint2 o;
    o.x = pack2(f2bf(v.x), f2bf(v.y));
    o.y = pack2(f2bf(v.z), f2bf(v.w));
    *reinterpret_cast<uint2*>(dst) = o;
  }
}

// --------------- GEMM1: h = xg @ w1^T, fused silu(gate)*up -> a (bf16) -----
// 128 rows x (64 gate + 64 up) cols, BK=32, swizzled LDS, async staging.
__global__ __launch_bounds__(256) void k_gemm1(
    const unsigned short* __restrict__ xg, const unsigned short* __restrict__ w1d,
    const int* __restrict__ ctrl, const int* __restrict__ tilemap,
    unsigned short* __restrict__ a_out) {
  __shared__ unsigned short sA[128 * 32];   // 8 KB
  __shared__ unsigned short sBg[64 * 32];   // 4 KB
  __shared__ unsigned short sBu[64 * 32];   // 4 KB
  int bid = blockIdx.x, tid = threadIdx.x;
  int nt = bid & 31, tile = bid >> 5;
  if (tile >= ctrl[25]) return;
  int tm = tilemap[tile];
  int e = tm >> 20, row0 = tm & 0xFFFFF;
  int n0 = nt * 64;
  int wave = tid >> 6, lane = tid & 63;
  int ln = lane & 15, quad = lane >> 4;
  int wr = (wave & 1) * 64, wc = (wave >> 1) * 32;

  int srow = tid >> 2, scblk = tid & 3;
  int scol = (scblk ^ ((srow >> 1) & 3)) * 8;
  const unsigned short* gA0 = xg + (size_t)(row0 + srow) * HIDDEN + scol;
  const unsigned short* gA1 = gA0 + (size_t)64 * HIDDEN;
  const unsigned short* gBg = w1d + ((size_t)e * 4096 + n0 + srow) * HIDDEN + scol;
  const unsigned short* gBu = gBg + (size_t)INTER * HIDDEN;
  unsigned short* lA0 = sA + tid * 8;
  unsigned short* lA1 = sA + 64 * 32 + tid * 8;
  unsigned short* lBg = sBg + tid * 8;
  unsigned short* lBu = sBu + tid * 8;

  f32x4 aG[4][2] = {}, aU[4][2] = {};
  for (int k0 = 0; k0 < HIDDEN; k0 += 32) {
    __syncthreads();
    gload16(gA0 + k0, lA0);
    gload16(gA1 + k0, lA1);
    gload16(gBg + k0, lBg);
    gload16(gBu + k0, lBu);
    __syncthreads();
    bf16x8 af[4], bg[2], bu[2];
#pragma unroll
    for (int m = 0; m < 4; m++) {
      int ar = wr + m * 16 + ln;
      af[m] = *reinterpret_cast<const bf16x8*>(&sA[ar * 32 + (quad ^ ((ar >> 1) & 3)) * 8]);
    }
#pragma unroll
    for (int n = 0; n < 2; n++) {
      int br = wc + n * 16 + ln;
      int bo = br * 32 + (quad ^ ((br >> 1) & 3)) * 8;
      bg[n] = *reinterpret_cast<const bf16x8*>(&sBg[bo]);
      bu[n] = *reinterpret_cast<const bf16x8*>(&sBu[bo]);
    }
#pragma unroll
    for (int m = 0; m < 4; m++)
#pragma unroll
      for (int n = 0; n < 2; n++) {
        aG[m][n] = __builtin_amdgcn_mfma_f32_16x16x32_bf16(af[m], bg[n], aG[m][n], 0, 0, 0);
        aU[m][n] = __builtin_amdgcn_mfma_f32_16x16x32_bf16(af[m], bu[n], aU[m][n], 0, 0, 0);
      }
  }
#pragma unroll
  for (int m = 0; m < 4; m++)
#pragma unroll
    for (int n = 0; n < 2; n++) {
      int col = n0 + wc + n * 16 + ln;
#pragma unroll
      for (int r = 0; r < 4; r++) {
        float g = aG[m][n][r], u = aU[m][n][r];
        float act = (g / (1.f + __expf(-g))) * u;
        int row = row0 + wr + m * 16 + quad * 4 + r;
        a_out[(size_t)row * INTER + col] = f2bf(act);
      }
    }
}

// --------------- GEMM2: y[slot] = a @ w2^T, 128x128, BK=32 -----------------
__global__ __launch_bounds__(256) void k_gemm2(
    const unsigned short* __restrict__ a_in, const unsigned short* __restrict__ w2d,
    const int* __restrict__ ctrl, const int* __restrict__ tilemap,
    unsigned short* __restrict__ y) {
  __shared__ unsigned short sA[128 * 32];   // 8 KB
  __shared__ unsigned short sB[128 * 32];   // 8 KB
  int bid = blockIdx.x, tid = threadIdx.x;
  int nt = bid & 7, tile = bid >> 3;
  if (tile >= ctrl[25]) return;
  int tm = tilemap[tile];
  int e = tm >> 20, row0 = tm & 0xFFFFF;
  int n0 = nt * 128;
  int wave = tid >> 6, lane = tid & 63;
  int ln = lane & 15, quad = lane >> 4;
  int wr = (wave & 1) * 64, wc = (wave >> 1) * 64;

  int srow = tid >> 2, scblk = tid & 3;
  int scol = (scblk ^ ((srow >> 1) & 3)) * 8;
  const unsigned short* gA0 = a_in + (size_t)(row0 + srow) * INTER + scol;
  const unsigned short* gA1 = gA0 + (size_t)64 * INTER;
  const unsigned short* gB0 = w2d + ((size_t)e * 1024 + n0 + srow) * INTER + scol;
  const unsigned short* gB1 = gB0 + (size_t)64 * INTER;
  unsigned short* lA0 = sA + tid * 8;
  unsigned short* lA1 = sA + 64 * 32 + tid * 8;
  unsigned short* lB0 = sB + tid * 8;
  unsigned short* lB1 = sB + 64 * 32 + tid * 8;

  f32x4 acc[4][4] = {};
  for (int k0 = 0; k0 < INTER; k0 += 32) {
    __syncthreads();
    gload16(gA0 + k0, lA0);
    gload16(gA1 + k0, lA1);
    gload16(gB0 + k0, lB0);
    gload16(gB1 + k0, lB1);
    __syncthreads();
    bf16x8 af[4], bf_[4];
#pragma unroll
    for (int m = 0; m < 4; m++) {
      int ar = wr + m * 16 + ln;
      af[m] = *reinterpret_cast<const bf16x8*>(&sA[ar * 32 + (quad ^ ((ar >> 1) & 3)) * 8]);
    }
#pragma unroll
    for (int n = 0; n < 4; n++) {
      int br = wc + n * 16 + ln;
      bf_[n] = *reinterpret_cast<const bf16x8*>(&sB[br * 32 + (quad ^ ((br >> 1) & 3)) * 8]);
    }
#pragma unroll
    for (int m = 0; m < 4; m++)
#pragma unroll
      for (int n = 0; n < 4; n++)
        acc[m][n] = __builtin_amdgcn_mfma_f32_16x16x32_bf16(af[m], bf_[n], acc[m][n], 0, 0, 0);
  }
#pragma unroll
  for (int m = 0; m < 4; m++)
#pragma unroll
    for (int n = 0; n < 4; n++) {
      int col = n0 + wc + n * 16 + ln;
#pragma unroll
      for (int r = 0; r < 4; r++) {
        int row = row0 + wr + m * 16 + quad * 4 + r;
        y[(size_t)row * HIDDEN + col] = f2bf(acc[m][n][r]);
      }
    }
}

// --------------- combine: out[t] = g0*y[s0] + g1*y[s1] ---------------------
__global__ __launch_bounds__(256) void k_combine(const unsigned short* __restrict__ y,
    const int* __restrict__ slots, const float* __restrict__ topkw,
    float* __restrict__ out) {
  int t = blockIdx.x;
  int c = threadIdx.x * 4;
  int s0 = slots[t * 2], s1 = slots[t * 2 + 1];
  float g0 = topkw[t * 2], g1 = topkw[t * 2 + 1];
  uint2 va = *reinterpret_cast<const uint2*>(y + (size_t)s0 * HIDDEN + c);
  uint2 vb = *reinterpret_cast<const uint2*>(y + (size_t)s1 * HIDDEN + c);
  float4 o;
  o.x = g0 * bf2f(va.x & 0xffffu) + g1 * bf2f(vb.x & 0xffffu);
  o.y = g0 * bf2f(va.x >> 16)     + g1 * bf2f(vb.x >> 16);
  o.z = g0 * bf2f(va.y & 0xffffu) + g1 * bf2f(vb.y & 0xffffu);
  o.w = g0 * bf2f(va.y >> 16)     + g1 * bf2f(vb.y >> 16);
  *reinterpret_cast<float4*>(out + (size_t)t * HIDDEN + c) = o;
}

extern "C" void kernel_launch(void* const* d_in, const int* in_sizes, int n_in,
                              void* d_out, int out_size, void* d_ws, size_t ws_size,
                              hipStream_t stream) {
  const float* x   = (const float*)d_in[0];
  const float* rw  = (const float*)d_in[1];
  const int*   w1  = (const int*)d_in[2];
  const float* w1s = (const float*)d_in[3];
  const int*   w2  = (const int*)d_in[4];
  const float* w2s = (const float*)d_in[5];
  float* out = (float*)d_out;
  char* ws = (char*)d_ws;

  int*   topki = (int*)(ws + OFF_TOPKI);
  float* topkw = (float*)(ws + OFF_TOPKW);
  int*   ctrl  = (int*)(ws + OFF_CTRL);
  int*   tok   = (int*)(ws + OFF_TOK);
  int*   slots = (int*)(ws + OFF_SLOT);
  int*   tilemap = (int*)(ws + OFF_TILE);
  unsigned short* xg  = (unsigned short*)(ws + OFF_XG);  // aliased as y after gemm1
  unsigned short* a   = (unsigned short*)(ws + OFF_A);
  unsigned short* w1d = (unsigned short*)(ws + OFF_W1D);
  unsigned short* w2d = (unsigned short*)(ws + OFF_W2D);

  k_prep<<<25600, 256, 0, stream>>>(x, rw, topki, topkw, w1, w1s, w1d, w2, w2s, w2d);
  k_route2<<<1, 256, 0, stream>>>(topki, ctrl, tok, slots, tilemap);
  k_gather<<<MAXROWS, 256, 0, stream>>>(x, ctrl, tok, xg);
  k_gemm1<<<32 * MAXTILES, 256, 0, stream>>>(xg, w1d, ctrl, tilemap, a);
  k_gemm2<<<8 * MAXTILES, 256, 0, stream>>>(a, w2d, ctrl, tilemap, xg /* y aliases xg */);
  k_combine<<<TOKENS, 256, 0, stream>>>(xg, slots, topkw, out);
}

// Round 7
// 320.218 us; speedup vs baseline: 1.0973x; 1.0401x over previous
//
#include <hip/hip_runtime.h>
#include <hip/hip_bf16.h>

#define HIDDEN 1024
#define INTER 2048
#define NE 8
#define GS 128
#define TOKENS 4096
#define MAXROWS 9216  // 8192 routed rows + 8*128 padding capacity
#define MAXTILES 72

typedef __bf16 bf16x8 __attribute__((ext_vector_type(8)));
typedef float f32x4 __attribute__((ext_vector_type(4)));

// ---- ws layout v3 (bytes) ----
#define OFF_TOPKI 0u               // int[4096][2]
#define OFF_TOPKW 32768u           // float[4096][2]
#define OFF_CTRL  65536u           // int[32]: [0..7]=counts [16..23]=offsets [24]=padded total [25]=ntiles
#define OFF_TOK   66048u           // int[MAXROWS]
#define OFF_SLOT  102912u          // int[TOKENS*2]
#define OFF_TILE  135680u          // int[MAXTILES] tile -> (e<<20 | row0)
#define OFF_XB    139776u          // bf16[TOKENS+1][HIDDEN]  (row TOKENS = zeros)
#define OFF_A     8530432u         // bf16[MAXROWS][INTER]
#define OFF_W1D   46279168u        // bf16[NE][4096][HIDDEN]  (dead after gemm1)
#define OFF_W2D   113388032u       // bf16[NE][1024][INTER]   -> 146942464 total
#define OFF_Y0    OFF_W1D          // bf16[MAXROWS][HIDDEN]   (aliases dead w1d)
#define OFF_Y1    (OFF_W1D + 18874368u)

__device__ __forceinline__ unsigned short f2bf(float f) {
  union { float f; unsigned int u; } v; v.f = f;
  unsigned int r = (v.u + 0x7FFFu + ((v.u >> 16) & 1u)) >> 16;
  return (unsigned short)r;
}
__device__ __forceinline__ float bf2f(unsigned int u) {
  union { unsigned int u; float f; } v; v.u = u << 16;
  return v.f;
}
__device__ __forceinline__ unsigned int pack2(unsigned short lo, unsigned short hi) {
  return (unsigned int)lo | ((unsigned int)hi << 16);
}

// async global->LDS, 16B per lane. LDS dest is wave-uniform base + lane*16.
typedef const __attribute__((address_space(1))) unsigned int GAS;
typedef __attribute__((address_space(3))) unsigned int LAS;
__device__ __forceinline__ void gload16(const unsigned short* g, unsigned short* l) {
  __builtin_amdgcn_global_load_lds((GAS*)g, (LAS*)l, 16, 0, 0);
}

// XOR swizzle (BK=32): LDS slot (row, cblk) holds global (row, cblk^((row>>1)&3)).
// Measured 0 bank conflicts (R4/R6).

// ---- prep: router | deq1 | deq2 | x->bf16 conv | zero-row ------------------
// block ranges: [0,1024) router, [1024,17408) deq1, [17408,25600) deq2,
//               [25600,29696) xconv, 29696 zero-row.  No LDS -> full occupancy.
__global__ __launch_bounds__(256) void k_prep(const float* __restrict__ x,
    const float* __restrict__ rw, int* __restrict__ topki, float* __restrict__ topkw,
    const int* __restrict__ w1, const float* __restrict__ w1s,
    unsigned short* __restrict__ w1d,
    const int* __restrict__ w2, const float* __restrict__ w2s,
    unsigned short* __restrict__ w2d, unsigned short* __restrict__ xb) {
  int bid = blockIdx.x, tid = threadIdx.x;
  if (bid == 29696) {
    uint2 z; z.x = 0u; z.y = 0u;
    *reinterpret_cast<uint2*>(xb + (size_t)TOKENS * HIDDEN + tid * 4) = z;
    return;
  }
  if (bid >= 25600) {
    // ---- xconv: fp32 -> bf16, token order ----
    size_t idx = (size_t)(bid - 25600) * 1024 + tid * 4;
    float4 v = *reinterpret_cast<const float4*>(x + idx);
    uint2 o;
    o.x = pack2(f2bf(v.x), f2bf(v.y));
    o.y = pack2(f2bf(v.z), f2bf(v.w));
    *reinterpret_cast<uint2*>(xb + idx) = o;
    return;
  }
  if (bid >= 17408) {
    // ---- deq2: 1024 int32 per row, 16 scales per row ----
    int gid = (bid - 17408) * 256 + tid;
    int i4 = gid * 4;
    int r = i4 >> 10;
    int i = i4 & 1023;
    float s = w2s[r * 16 + (i >> 6)];
    int4 p = *reinterpret_cast<const int4*>(w2 + (size_t)i4);
    int pv[4] = { p.x, p.y, p.z, p.w };
    uint4 o; unsigned int ov[4];
#pragma unroll
    for (int j = 0; j < 4; j++) {
      float lo = (float)((pv[j] & 15) - 8) * s;
      float hi = (float)(((pv[j] >> 4) & 15) - 8) * s;
      ov[j] = pack2(f2bf(lo), f2bf(hi));
    }
    o.x = ov[0]; o.y = ov[1]; o.z = ov[2]; o.w = ov[3];
    *reinterpret_cast<uint4*>(w2d + ((size_t)r << 11) + 2 * i) = o;
    return;
  }
  if (bid >= 1024) {
    // ---- deq1: 512 int32 per row, 8 scales per row ----
    int gid = (bid - 1024) * 256 + tid;
    int i4 = gid * 4;
    int r = i4 >> 9;
    int i = i4 & 511;
    float s = w1s[r * 8 + (i >> 6)];
    int4 p = *reinterpret_cast<const int4*>(w1 + (size_t)i4);
    int pv[4] = { p.x, p.y, p.z, p.w };
    uint4 o; unsigned int ov[4];
#pragma unroll
    for (int j = 0; j < 4; j++) {
      float lo = (float)((pv[j] & 15) - 8) * s;
      float hi = (float)(((pv[j] >> 4) & 15) - 8) * s;
      ov[j] = pack2(f2bf(lo), f2bf(hi));
    }
    o.x = ov[0]; o.y = ov[1]; o.z = ov[2]; o.w = ov[3];
    *reinterpret_cast<uint4*>(w1d + ((size_t)r << 10) + 2 * i) = o;
    return;
  }
  // ---- router ----
  int wave = tid >> 6, lane = tid & 63;
  int t = bid * 4 + wave;
  float acc[NE];
#pragma unroll
  for (int e = 0; e < NE; e++) acc[e] = 0.f;
  const float* xr = x + (size_t)t * HIDDEN;
  for (int i = lane; i < HIDDEN; i += 64) {
    float xv = xr[i];
#pragma unroll
    for (int e = 0; e < NE; e++) acc[e] += xv * rw[e * HIDDEN + i];
  }
#pragma unroll
  for (int e = 0; e < NE; e++) {
    float v = acc[e];
    for (int off = 32; off > 0; off >>= 1) v += __shfl_down(v, off, 64);
    acc[e] = v;
  }
  if (lane == 0) {
    int b0 = 0; float s0 = acc[0];
#pragma unroll
    for (int e = 1; e < NE; e++) if (acc[e] > s0) { s0 = acc[e]; b0 = e; }
    int b1 = -1; float s1 = -3.0e38f;
#pragma unroll
    for (int e = 0; e < NE; e++) if (e != b0 && acc[e] > s1) { s1 = acc[e]; b1 = e; }
    float w0 = 1.f / (1.f + __expf(s1 - s0));
    topki[t * 2] = b0; topki[t * 2 + 1] = b1;
    topkw[t * 2] = w0; topkw[t * 2 + 1] = 1.f - w0;
  }
}

// ------- route2 (1 block): hist + offsets + tilemap + pad fill + scatter ----
__global__ __launch_bounds__(256) void k_route2(const int* __restrict__ topki,
    int* __restrict__ ctrl, int* __restrict__ tok, int* __restrict__ slots,
    int* __restrict__ tilemap) {
  __shared__ int h[NE], off[NE], cnt[NE];
  int tid = threadIdx.x;
  if (tid < NE) h[tid] = 0;
  __syncthreads();
  for (int i = tid; i < TOKENS * 2; i += 256) atomicAdd(&h[topki[i]], 1);
  __syncthreads();
  if (tid == 0) {
    int run = 0, t = 0;
    for (int e = 0; e < NE; e++) {
      int c = h[e];
      ctrl[e] = c; ctrl[16 + e] = run; off[e] = run;
      int pc = (c + 127) & ~127;
      for (int mt = 0; mt < (pc >> 7); mt++) tilemap[t++] = (e << 20) | (run + mt * 128);
      run += pc;
    }
    ctrl[24] = run; ctrl[25] = t;
  }
  __syncthreads();
#pragma unroll
  for (int e = 0; e < NE; e++) {
    int c = h[e], pc = (c + 127) & ~127;
    for (int i = c + tid; i < pc; i += 256) tok[off[e] + i] = -1;
  }
  if (tid < NE) cnt[tid] = off[tid];
  __syncthreads();
  for (int i = tid; i < TOKENS * 2; i += 256) {
    int e = topki[i];
    int p = atomicAdd(&cnt[e], 1);
    tok[p] = i >> 1;
    slots[i] = p;
  }
}

// --------------- GEMM1: h = gather(xb) @ w1^T, silu(gate)*up -> a ----------
// 128 rows x (64 gate + 64 up) cols, BK=32, swizzled LDS, async staging.
// A rows gathered directly from token-order xb via tok[] (pad -> zero row).
__global__ __launch_bounds__(256) void k_gemm1(
    const unsigned short* __restrict__ xb, const unsigned short* __restrict__ w1d,
    const int* __restrict__ ctrl, const int* __restrict__ tilemap,
    const int* __restrict__ tok, unsigned short* __restrict__ a_out) {
  __shared__ unsigned short sA[128 * 32];   // 8 KB
  __shared__ unsigned short sBg[64 * 32];   // 4 KB
  __shared__ unsigned short sBu[64 * 32];   // 4 KB
  int bid = blockIdx.x, tid = threadIdx.x;
  int nt = bid & 31, tile = bid >> 5;
  if (tile >= ctrl[25]) return;
  int tm = tilemap[tile];
  int e = tm >> 20, row0 = tm & 0xFFFFF;
  int n0 = nt * 64;
  int wave = tid >> 6, lane = tid & 63;
  int ln = lane & 15, quad = lane >> 4;
  int wr = (wave & 1) * 64, wc = (wave >> 1) * 32;

  int srow = tid >> 2, scblk = tid & 3;
  int scol = (scblk ^ ((srow >> 1) & 3)) * 8;
  int t0 = tok[row0 + srow];
  int t1 = tok[row0 + 64 + srow];
  const unsigned short* gA0 = xb + (size_t)(t0 < 0 ? TOKENS : t0) * HIDDEN + scol;
  const unsigned short* gA1 = xb + (size_t)(t1 < 0 ? TOKENS : t1) * HIDDEN + scol;
  const unsigned short* gBg = w1d + ((size_t)e * 4096 + n0 + srow) * HIDDEN + scol;
  const unsigned short* gBu = gBg + (size_t)INTER * HIDDEN;
  unsigned short* lA0 = sA + tid * 8;
  unsigned short* lA1 = sA + 64 * 32 + tid * 8;
  unsigned short* lBg = sBg + tid * 8;
  unsigned short* lBu = sBu + tid * 8;

  f32x4 aG[4][2] = {}, aU[4][2] = {};
  for (int k0 = 0; k0 < HIDDEN; k0 += 32) {
    __syncthreads();
    gload16(gA0 + k0, lA0);
    gload16(gA1 + k0, lA1);
    gload16(gBg + k0, lBg);
    gload16(gBu + k0, lBu);
    __syncthreads();
    bf16x8 af[4], bg[2], bu[2];
#pragma unroll
    for (int m = 0; m < 4; m++) {
      int ar = wr + m * 16 + ln;
      af[m] = *reinterpret_cast<const bf16x8*>(&sA[ar * 32 + (quad ^ ((ar >> 1) & 3)) * 8]);
    }
#pragma unroll
    for (int n = 0; n < 2; n++) {
      int br = wc + n * 16 + ln;
      int bo = br * 32 + (quad ^ ((br >> 1) & 3)) * 8;
      bg[n] = *reinterpret_cast<const bf16x8*>(&sBg[bo]);
      bu[n] = *reinterpret_cast<const bf16x8*>(&sBu[bo]);
    }
#pragma unroll
    for (int m = 0; m < 4; m++)
#pragma unroll
      for (int n = 0; n < 2; n++) {
        aG[m][n] = __builtin_amdgcn_mfma_f32_16x16x32_bf16(af[m], bg[n], aG[m][n], 0, 0, 0);
        aU[m][n] = __builtin_amdgcn_mfma_f32_16x16x32_bf16(af[m], bu[n], aU[m][n], 0, 0, 0);
      }
  }
#pragma unroll
  for (int m = 0; m < 4; m++)
#pragma unroll
    for (int n = 0; n < 2; n++) {
      int col = n0 + wc + n * 16 + ln;
#pragma unroll
      for (int r = 0; r < 4; r++) {
        float g = aG[m][n][r], u = aU[m][n][r];
        float act = (g / (1.f + __expf(-g))) * u;
        int row = row0 + wr + m * 16 + quad * 4 + r;
        a_out[(size_t)row * INTER + col] = f2bf(act);
      }
    }
}

// ------- GEMM2 split-K x2: y[kp][slot] = a[:,kp*1024:+1024] @ w2^T ---------
// 128x128 tile, BK=32. bid: kp = bid&1, nt = (bid>>1)&7, tile = bid>>4.
__global__ __launch_bounds__(256) void k_gemm2(
    const unsigned short* __restrict__ a_in, const unsigned short* __restrict__ w2d,
    const int* __restrict__ ctrl, const int* __restrict__ tilemap,
    unsigned short* __restrict__ y) {
  __shared__ unsigned short sA[128 * 32];   // 8 KB
  __shared__ unsigned short sB[128 * 32];   // 8 KB
  int bid = blockIdx.x, tid = threadIdx.x;
  int kp = bid & 1, nt = (bid >> 1) & 7, tile = bid >> 4;
  if (tile >= ctrl[25]) return;
  int tm = tilemap[tile];
  int e = tm >> 20, row0 = tm & 0xFFFFF;
  int n0 = nt * 128;
  int wave = tid >> 6, lane = tid & 63;
  int ln = lane & 15, quad = lane >> 4;
  int wr = (wave & 1) * 64, wc = (wave >> 1) * 64;

  int srow = tid >> 2, scblk = tid & 3;
  int scol = (scblk ^ ((srow >> 1) & 3)) * 8;
  int kbase = kp * (INTER / 2);
  const unsigned short* gA0 = a_in + (size_t)(row0 + srow) * INTER + kbase + scol;
  const unsigned short* gA1 = gA0 + (size_t)64 * INTER;
  const unsigned short* gB0 = w2d + ((size_t)e * 1024 + n0 + srow) * INTER + kbase + scol;
  const unsigned short* gB1 = gB0 + (size_t)64 * INTER;
  unsigned short* lA0 = sA + tid * 8;
  unsigned short* lA1 = sA + 64 * 32 + tid * 8;
  unsigned short* lB0 = sB + tid * 8;
  unsigned short* lB1 = sB + 64 * 32 + tid * 8;

  f32x4 acc[4][4] = {};
  for (int k0 = 0; k0 < INTER / 2; k0 += 32) {
    __syncthreads();
    gload16(gA0 + k0, lA0);
    gload16(gA1 + k0, lA1);
    gload16(gB0 + k0, lB0);
    gload16(gB1 + k0, lB1);
    __syncthreads();
    bf16x8 af[4], bf_[4];
#pragma unroll
    for (int m = 0; m < 4; m++) {
      int ar = wr + m * 16 + ln;
      af[m] = *reinterpret_cast<const bf16x8*>(&sA[ar * 32 + (quad ^ ((ar >> 1) & 3)) * 8]);
    }
#pragma unroll
    for (int n = 0; n < 4; n++) {
      int br = wc + n * 16 + ln;
      bf_[n] = *reinterpret_cast<const bf16x8*>(&sB[br * 32 + (quad ^ ((br >> 1) & 3)) * 8]);
    }
#pragma unroll
    for (int m = 0; m < 4; m++)
#pragma unroll
      for (int n = 0; n < 4; n++)
        acc[m][n] = __builtin_amdgcn_mfma_f32_16x16x32_bf16(af[m], bf_[n], acc[m][n], 0, 0, 0);
  }
  unsigned short* yk = y + (size_t)kp * MAXROWS * HIDDEN;
#pragma unroll
  for (int m = 0; m < 4; m++)
#pragma unroll
    for (int n = 0; n < 4; n++) {
      int col = n0 + wc + n * 16 + ln;
#pragma unroll
      for (int r = 0; r < 4; r++) {
        int row = row0 + wr + m * 16 + quad * 4 + r;
        yk[(size_t)row * HIDDEN + col] = f2bf(acc[m][n][r]);
      }
    }
}

// ------- combine: out[t] = g0*(y0[s0]+y1[s0]) + g1*(y0[s1]+y1[s1]) ---------
__global__ __launch_bounds__(256) void k_combine(const unsigned short* __restrict__ y,
    const int* __restrict__ slots, const float* __restrict__ topkw,
    float* __restrict__ out) {
  int t = blockIdx.x;
  int c = threadIdx.x * 4;
  int s0 = slots[t * 2], s1 = slots[t * 2 + 1];
  float g0 = topkw[t * 2], g1 = topkw[t * 2 + 1];
  const unsigned short* y1 = y + (size_t)MAXROWS * HIDDEN;
  uint2 a0 = *reinterpret_cast<const uint2*>(y  + (size_t)s0 * HIDDEN + c);
  uint2 a1 = *reinterpret_cast<const uint2*>(y1 + (size_t)s0 * HIDDEN + c);
  uint2 b0 = *reinterpret_cast<const uint2*>(y  + (size_t)s1 * HIDDEN + c);
  uint2 b1 = *reinterpret_cast<const uint2*>(y1 + (size_t)s1 * HIDDEN + c);
  float4 o;
  o.x = g0 * (bf2f(a0.x & 0xffffu) + bf2f(a1.x & 0xffffu))
      + g1 * (bf2f(b0.x & 0xffffu) + bf2f(b1.x & 0xffffu));
  o.y = g0 * (bf2f(a0.x >> 16) + bf2f(a1.x >> 16))
      + g1 * (bf2f(b0.x >> 16) + bf2f(b1.x >> 16));
  o.z = g0 * (bf2f(a0.y & 0xffffu) + bf2f(a1.y & 0xffffu))
      + g1 * (bf2f(b0.y & 0xffffu) + bf2f(b1.y & 0xffffu));
  o.w = g0 * (bf2f(a0.y >> 16) + bf2f(a1.y >> 16))
      + g1 * (bf2f(b0.y >> 16) + bf2f(b1.y >> 16));
  *reinterpret_cast<float4*>(out + (size_t)t * HIDDEN + c) = o;
}

extern "C" void kernel_launch(void* const* d_in, const int* in_sizes, int n_in,
                              void* d_out, int out_size, void* d_ws, size_t ws_size,
                              hipStream_t stream) {
  const float* x   = (const float*)d_in[0];
  const float* rw  = (const float*)d_in[1];
  const int*   w1  = (const int*)d_in[2];
  const float* w1s = (const float*)d_in[3];
  const int*   w2  = (const int*)d_in[4];
  const float* w2s = (const float*)d_in[5];
  float* out = (float*)d_out;
  char* ws = (char*)d_ws;

  int*   topki = (int*)(ws + OFF_TOPKI);
  float* topkw = (float*)(ws + OFF_TOPKW);
  int*   ctrl  = (int*)(ws + OFF_CTRL);
  int*   tok   = (int*)(ws + OFF_TOK);
  int*   slots = (int*)(ws + OFF_SLOT);
  int*   tilemap = (int*)(ws + OFF_TILE);
  unsigned short* xb  = (unsigned short*)(ws + OFF_XB);
  unsigned short* a   = (unsigned short*)(ws + OFF_A);
  unsigned short* w1d = (unsigned short*)(ws + OFF_W1D);
  unsigned short* w2d = (unsigned short*)(ws + OFF_W2D);
  unsigned short* y   = (unsigned short*)(ws + OFF_Y0);  // y1 = y + MAXROWS*HIDDEN

  k_prep<<<29697, 256, 0, stream>>>(x, rw, topki, topkw, w1, w1s, w1d, w2, w2s, w2d, xb);
  k_route2<<<1, 256, 0, stream>>>(topki, ctrl, tok, slots, tilemap);
  k_gemm1<<<32 * MAXTILES, 256, 0, stream>>>(xb, w1d, ctrl, tilemap, tok, a);
  k_gemm2<<<16 * MAXTILES, 256, 0, stream>>>(a, w2d, ctrl, tilemap, y);
  k_combine<<<TOKENS, 256, 0, stream>>>(y, slots, topkw, out);
}